// Round 1
// baseline (7406.960 us; speedup 1.0000x reference)
//
#include <hip/hip_runtime.h>
#include <stdint.h>

#define T_STEPS 101
#define ROWS 1600
#define NTHR 512
#define NZ1 40
#define NZ2 50
#define OFF2 (NZ1 * ROWS)              /* 64000  */
#define OFF3 (OFF2 + NZ2 * ROWS)       /* 144000 */
#define NZTOT (OFF3 + NZ2 * ROWS)      /* 224000 */

__device__ __forceinline__ float sigmoidf(float v) { return 1.0f / (1.0f + expf(-v)); }

// ---------------------------------------------------------------------------
// Prep: extract fixed-length CSR (exactly 40/50 nonzeros per row by mask
// construction) from the masked dense weights. SoA layout vals[j*1600 + r]
// so the main kernel's weight stream is lane-coalesced.
// ---------------------------------------------------------------------------
__global__ void prep_kernel(const float* __restrict__ W1, const float* __restrict__ W2,
                            const float* __restrict__ W3,
                            float* __restrict__ vals, uint16_t* __restrict__ cols) {
  int gid = blockIdx.x * blockDim.x + threadIdx.x;
  if (gid >= 3 * ROWS) return;
  int l = gid / ROWS, r = gid - l * ROWS;
  const float* W; int in_f, knz, off;
  if (l == 0)      { W = W1; in_f = 320; knz = NZ1; off = 0;    }
  else if (l == 1) { W = W2; in_f = 400; knz = NZ2; off = OFF2; }
  else             { W = W3; in_f = 400; knz = NZ2; off = OFF3; }
  float* v = vals + off;
  uint16_t* c = cols + off;
  int cnt = 0;
  for (int col = 0; col < in_f; ++col) {
    float w = W[(size_t)r * in_f + col];
    if (w != 0.0f) {
      if (cnt < knz) { v[cnt * ROWS + r] = w; c[cnt * ROWS + r] = (uint16_t)col; }
      ++cnt;
    }
  }
  for (; cnt < knz; ++cnt) { v[cnt * ROWS + r] = 0.0f; c[cnt * ROWS + r] = 0; }
}

// ---------------------------------------------------------------------------
// One layer's step for this thread's row slots.
// Rows: slot i<3 -> r = tid + 512*i ; slot 3 -> r = 1536 + tid (wave 0 only).
// Lane groups of 8 (8-aligned tids) own one neuron's 8 branches.
// ---------------------------------------------------------------------------
template<int L, int KNZ, bool U8>
__device__ __forceinline__ void layer_step(
    int tid,
    const float* __restrict__ vals, const uint16_t* __restrict__ cols,
    float (&d)[3][4][4],
    const float (&beta)[3][4], const float (&bia)[3][4], const float (&alpha)[3][4],
    const float (*k1f)[4], const uint8_t (*k23)[4],
    uint8_t (*s_l)[4], float (*mem_l)[4])
{
#pragma unroll
  for (int i = 0; i < 4; ++i) {
    if (i == 3 && tid >= 64) break;          // wave-uniform: only wave 0 has slot 3
    const int r = (i < 3) ? (tid + NTHR * i) : (1536 + tid);
    float a0 = bia[L][i], a1 = a0, a2 = a0, a3 = a0;
    const float* vp = vals + r;
    const uint16_t* cp = cols + r;
#pragma unroll 10
    for (int j = 0; j < KNZ; ++j) {
      const float w = vp[(size_t)j * ROWS];
      const int c = cp[(size_t)j * ROWS];
      if constexpr (U8) {
        const uint32_t s4 = *reinterpret_cast<const uint32_t*>(k23[c]);
        a0 = fmaf(w, (float)(s4 & 0xffu), a0);
        a1 = fmaf(w, (float)((s4 >> 8) & 0xffu), a1);
        a2 = fmaf(w, (float)((s4 >> 16) & 0xffu), a2);
        a3 = fmaf(w, (float)(s4 >> 24), a3);
      } else {
        const float4 kv = *reinterpret_cast<const float4*>(k1f[c]);
        a0 = fmaf(w, kv.x, a0);
        a1 = fmaf(w, kv.y, a1);
        a2 = fmaf(w, kv.z, a2);
        a3 = fmaf(w, kv.w, a3);
      }
    }
    // d = beta*d + (1-beta)*ff
    const float bt = beta[L][i], ob = 1.0f - bt;
    float d0 = fmaf(bt, d[L][i][0], ob * a0);
    float d1 = fmaf(bt, d[L][i][1], ob * a1);
    float d2 = fmaf(bt, d[L][i][2], ob * a2);
    float d3 = fmaf(bt, d[L][i][3], ob * a3);
    d[L][i][0] = d0; d[L][i][1] = d1; d[L][i][2] = d2; d[L][i][3] = d3;
    // branch sum over the neuron's 8 rows (8 consecutive, 8-aligned lanes)
    d0 += __shfl_xor(d0, 1); d0 += __shfl_xor(d0, 2); d0 += __shfl_xor(d0, 4);
    d1 += __shfl_xor(d1, 1); d1 += __shfl_xor(d1, 2); d1 += __shfl_xor(d1, 4);
    d2 += __shfl_xor(d2, 1); d2 += __shfl_xor(d2, 2); d2 += __shfl_xor(d2, 4);
    d3 += __shfl_xor(d3, 1); d3 += __shfl_xor(d3, 2); d3 += __shfl_xor(d3, 4);
    if ((tid & 7) == 0) {
      const int n = r >> 3;
      const float al = alpha[L][i], oa = 1.0f - al;
      float4 mv = *reinterpret_cast<float4*>(&mem_l[n][0]);
      const uint32_t so = *reinterpret_cast<uint32_t*>(&s_l[n][0]);
      // mem = (mem - vth*spike)*alpha + (1-alpha)*sum(d)
      const float m0 = fmaf(mv.x - (float)(so & 0xffu),         al, oa * d0);
      const float m1 = fmaf(mv.y - (float)((so >> 8) & 0xffu),  al, oa * d1);
      const float m2 = fmaf(mv.z - (float)((so >> 16) & 0xffu), al, oa * d2);
      const float m3 = fmaf(mv.w - (float)(so >> 24),           al, oa * d3);
      *reinterpret_cast<float4*>(&mem_l[n][0]) = make_float4(m0, m1, m2, m3);
      const uint32_t sn = (m0 > 1.0f ? 1u : 0u)
                        | (m1 > 1.0f ? 0x100u : 0u)
                        | (m2 > 1.0f ? 0x10000u : 0u)
                        | (m3 > 1.0f ? 0x1000000u : 0u);
      *reinterpret_cast<uint32_t*>(&s_l[n][0]) = sn;
    }
  }
}

// ---------------------------------------------------------------------------
// Persistent main kernel: 256 blocks x 512 threads, 4 batch elements / block.
// ---------------------------------------------------------------------------
__global__ void __launch_bounds__(NTHR, 2)
snn_main(const float* __restrict__ x,
         const float* __restrict__ b1, const float* __restrict__ tm1, const float* __restrict__ tn1,
         const float* __restrict__ b2, const float* __restrict__ tm2, const float* __restrict__ tn2,
         const float* __restrict__ b3, const float* __restrict__ tm3, const float* __restrict__ tn3,
         const float* __restrict__ W4, const float* __restrict__ b4, const float* __restrict__ tm4,
         const float* __restrict__ vals, const uint16_t* __restrict__ cols,
         float* __restrict__ out)
{
  __shared__ __align__(16) float   k1f[320][4];       // layer-1 input (x real-valued + s1)
  __shared__ __align__(4)  uint8_t k23[400][4];       // layer-2/3 input (binary spikes)
  __shared__ __align__(4)  uint8_t s_lds[3][200][4];  // spike state (exact 0/1)
  __shared__ __align__(16) float   mem_lds[3][200][4];
  __shared__ float w4_lds[12][201];                   // padded: stride 201 breaks bank stride

  const int tid = threadIdx.x;
  const int bg  = blockIdx.x;          // batch group: batches bg*4 .. bg*4+3

  // zero states
  for (int idx = tid; idx < 3 * 200; idx += NTHR) {
    reinterpret_cast<uint32_t*>(&s_lds[0][0][0])[idx] = 0u;
    float4* mp = reinterpret_cast<float4*>(&mem_lds[0][0][0]);
    mp[idx] = make_float4(0.f, 0.f, 0.f, 0.f);
  }
  for (int idx = tid; idx < 12 * 200; idx += NTHR)
    w4_lds[idx / 200][idx % 200] = W4[idx];

  float d[3][4][4];
#pragma unroll
  for (int l = 0; l < 3; ++l)
#pragma unroll
    for (int i = 0; i < 4; ++i)
#pragma unroll
      for (int b = 0; b < 4; ++b) d[l][i][b] = 0.0f;

  float beta[3][4], bia[3][4], alpha[3][4];
#pragma unroll
  for (int i = 0; i < 4; ++i) {
    const int r = (i < 3) ? (tid + NTHR * i) : (1536 + (tid & 63));
    const int n = r >> 3;
    beta[0][i] = sigmoidf(tn1[r]); bia[0][i] = b1[r]; alpha[0][i] = sigmoidf(tm1[n]);
    beta[1][i] = sigmoidf(tn2[r]); bia[1][i] = b2[r]; alpha[1][i] = sigmoidf(tm2[n]);
    beta[2][i] = sigmoidf(tn3[r]); bia[2][i] = b3[r]; alpha[2][i] = sigmoidf(tm3[n]);
  }

  float m4_reg = 0.0f, m4_acc = 0.0f, a4 = 0.0f, b4r = 0.0f;
  if (tid < 48) { const int o = tid >> 2; a4 = sigmoidf(tm4[o]); b4r = b4[o]; }
  __syncthreads();

  for (int t = 0; t < T_STEPS; ++t) {
    // ---- build k1 = [x_t | s1(old)] -----------------------------------
    if (tid < 480) {
      const int bat = tid / 120, cf = tid - bat * 120;
      const int c = cf / 40, f = cf - c * 40;
      const int b = bg * 4 + bat;
      k1f[cf][bat] = x[(((size_t)b * 3 + c) * T_STEPS + t) * 40 + f];
    }
    if (tid < 200) {
      const uint32_t so = reinterpret_cast<const uint32_t*>(&s_lds[0][0][0])[tid];
      *reinterpret_cast<float4*>(&k1f[120 + tid][0]) =
          make_float4((float)(so & 0xffu), (float)((so >> 8) & 0xffu),
                      (float)((so >> 16) & 0xffu), (float)(so >> 24));
    }
    __syncthreads();
    layer_step<0, NZ1, false>(tid, vals, cols, d, beta, bia, alpha,
                              k1f, k23, s_lds[0], mem_lds[0]);
    __syncthreads();
    // ---- build k2 = [s1(new) | s2(old)] -------------------------------
    if (tid < 200)
      reinterpret_cast<uint32_t*>(&k23[0][0])[tid] =
          reinterpret_cast<const uint32_t*>(&s_lds[0][0][0])[tid];
    else if (tid < 400)
      reinterpret_cast<uint32_t*>(&k23[0][0])[tid] =
          reinterpret_cast<const uint32_t*>(&s_lds[1][0][0])[tid - 200];
    __syncthreads();
    layer_step<1, NZ2, true>(tid, vals + OFF2, cols + OFF2, d, beta, bia, alpha,
                             k1f, k23, s_lds[1], mem_lds[1]);
    __syncthreads();
    // ---- build k3 = [s2(new) | s3(old)] -------------------------------
    if (tid < 200)
      reinterpret_cast<uint32_t*>(&k23[0][0])[tid] =
          reinterpret_cast<const uint32_t*>(&s_lds[1][0][0])[tid];
    else if (tid < 400)
      reinterpret_cast<uint32_t*>(&k23[0][0])[tid] =
          reinterpret_cast<const uint32_t*>(&s_lds[2][0][0])[tid - 200];
    __syncthreads();
    layer_step<2, NZ2, true>(tid, vals + OFF3, cols + OFF3, d, beta, bia, alpha,
                             k1f, k23, s_lds[2], mem_lds[2]);
    __syncthreads();
    // ---- leaky readout ------------------------------------------------
    if (tid < 48) {
      const int o = tid >> 2, bat = tid & 3;
      float dot = b4r;
#pragma unroll 8
      for (int n = 0; n < 200; ++n)
        dot = fmaf(w4_lds[o][n], (float)s_lds[2][n][bat], dot);
      m4_reg = a4 * m4_reg + (1.0f - a4) * dot;
      m4_acc += m4_reg;
    }
    __syncthreads();
  }

  // ---- log_softmax(acc / T) -------------------------------------------
  if (tid < 48) {
    const int o = tid >> 2, bat = tid & 3;
    k1f[o][bat] = m4_acc * (1.0f / (float)T_STEPS);
  }
  __syncthreads();
  if (tid < 4) {
    const int bat = tid;
    float v[12], mx = -1e30f;
#pragma unroll
    for (int o = 0; o < 12; ++o) { v[o] = k1f[o][bat]; mx = fmaxf(mx, v[o]); }
    float s = 0.0f;
#pragma unroll
    for (int o = 0; o < 12; ++o) s += expf(v[o] - mx);
    const float ls = logf(s);
#pragma unroll
    for (int o = 0; o < 12; ++o)
      out[((size_t)(bg * 4 + bat)) * 12 + o] = v[o] - mx - ls;
  }
}

// ---------------------------------------------------------------------------
extern "C" void kernel_launch(void* const* d_in, const int* in_sizes, int n_in,
                              void* d_out, int out_size, void* d_ws, size_t ws_size,
                              hipStream_t stream) {
  (void)in_sizes; (void)n_in; (void)out_size; (void)ws_size;
  const float* x   = (const float*)d_in[0];
  const float* W1  = (const float*)d_in[1];
  const float* b1  = (const float*)d_in[2];
  const float* tm1 = (const float*)d_in[3];
  const float* tn1 = (const float*)d_in[4];
  const float* W2  = (const float*)d_in[5];
  const float* b2  = (const float*)d_in[6];
  const float* tm2 = (const float*)d_in[7];
  const float* tn2 = (const float*)d_in[8];
  const float* W3  = (const float*)d_in[9];
  const float* b3  = (const float*)d_in[10];
  const float* tm3 = (const float*)d_in[11];
  const float* tn3 = (const float*)d_in[12];
  const float* W4  = (const float*)d_in[13];
  const float* b4  = (const float*)d_in[14];
  const float* tm4 = (const float*)d_in[15];

  float*    vals = (float*)d_ws;                                  // 224000 floats
  uint16_t* cols = (uint16_t*)((char*)d_ws + NZTOT * sizeof(float)); // 224000 u16

  prep_kernel<<<dim3(19), dim3(256), 0, stream>>>(W1, W2, W3, vals, cols);
  snn_main<<<dim3(256), dim3(NTHR), 0, stream>>>(
      x, b1, tm1, tn1, b2, tm2, tn2, b3, tm3, tn3, W4, b4, tm4,
      vals, cols, (float*)d_out);
}